// Round 1
// baseline (31.103 us; speedup 1.0000x reference)
//
#include <hip/hip_runtime.h>
#include <cstdint>

#define NTYPES 39
#define NA 64
#define WPB 4   // waves (molecules) per block

// spread 32 bits to even positions of a 64-bit word (morton)
__device__ __forceinline__ uint64_t spread32(uint32_t v){
  uint64_t x = v;
  x = (x | (x << 16)) & 0x0000FFFF0000FFFFull;
  x = (x | (x << 8))  & 0x00FF00FF00FF00FFull;
  x = (x | (x << 4))  & 0x0F0F0F0F0F0F0F0Full;
  x = (x | (x << 2))  & 0x3333333333333333ull;
  x = (x | (x << 1))  & 0x5555555555555555ull;
  return x;
}
// compress even bits of a 64-bit word to 32 bits (inverse morton)
__device__ __forceinline__ uint32_t compress_even(uint64_t x){
  x &= 0x5555555555555555ull;
  x = (x | (x >> 1))  & 0x3333333333333333ull;
  x = (x | (x >> 2))  & 0x0F0F0F0F0F0F0F0Full;
  x = (x | (x >> 4))  & 0x00FF00FF00FF00FFull;
  x = (x | (x >> 8))  & 0x0000FFFF0000FFFFull;
  x = (x | (x >> 16)) & 0x00000000FFFFFFFFull;
  return (uint32_t)x;
}

__global__ __launch_bounds__(WPB*64) void vcharge_kernel(
    const int*   __restrict__ atoms,
    const float* __restrict__ A,
    const float* __restrict__ Q,
    const float* __restrict__ e,
    const float* __restrict__ s,
    const float* __restrict__ alpha,
    const float* __restrict__ beta_p,
    float*       __restrict__ out,
    int B)
{
  __shared__ float tab[NTYPES*NTYPES];  // signed |de|^beta by (type_i, type_j)
  __shared__ float bw2[8];              // bond+aromatic weight by (af | aromboth<<2)

  const int tid = threadIdx.x;
  const float beta = beta_p[0];

  // Per-block table fill: 1521 powf over 256 threads (~6 each) — negligible.
  for (int k = tid; k < NTYPES*NTYPES; k += WPB*64){
    int a = k / NTYPES;
    int b = k - a*NTYPES;
    float d = e[b] - e[a];
    float t = powf(fabsf(d), beta);
    tab[k] = (d > 0.f) ? t : ((d < 0.f) ? -t : 0.f);
  }
  if (tid < 8){
    float a0 = alpha[0], a1 = alpha[1], a2 = alpha[2], a3 = alpha[3];
    int af = tid & 3;
    float bv = (af == 1) ? a0 : ((af == 2) ? a1 : ((af == 3) ? a2 : 0.f));
    if ((tid & 4) && af != 0) bv += a3;   // marom needs Af>0 AND both aromatic
    bw2[tid] = bv;
  }
  __syncthreads();

  const float alpha4 = alpha[4];
  const int wid  = tid >> 6;
  const int lane = tid & 63;
  const int m = blockIdx.x * WPB + wid;
  if (m >= B) return;

  const float* Am = A + (size_t)m * (NA*NA);
  const int ty = atoms[m*NA + lane];
  const float sinv = 1.0f / s[ty];
  const uint64_t AROM = (1ull<<6)|(1ull<<10)|(1ull<<19)|(1ull<<20)|(1ull<<21)|(1ull<<22)|(1ull<<32);
  const int aromt = (int)((AROM >> ty) & 1ull);
  const uint64_t aromBits = __ballot(aromt);     // wave-uniform
  const int tabrow = ty * NTYPES;                // read by others via readlane

  // --- Load phase: coalesced column loads; rows recovered via ballot ---
  uint64_t plo = 0, phi = 0, rb0 = 0, rb1 = 0;
  #pragma unroll
  for (int i = 0; i < 32; ++i){
    float v = Am[i*NA + lane];      // A[i][lane], coalesced 256B/wave
    int a = (int)v;                 // exact: values 0..3
    plo |= ((uint64_t)(uint32_t)a) << (2*i);
    uint64_t b0 = __ballot(a & 1);
    uint64_t b1 = __ballot(a & 2);
    if (lane == i){ rb0 = b0; rb1 = b1; }   // capture own row's bitplanes
  }
  #pragma unroll
  for (int i = 32; i < 64; ++i){
    float v = Am[i*NA + lane];
    int a = (int)v;
    phi |= ((uint64_t)(uint32_t)a) << (2*(i-32));
    uint64_t b0 = __ballot(a & 1);
    uint64_t b1 = __ballot(a & 2);
    if (lane == i){ rb0 = b0; rb1 = b1; }
  }
  // Merge transpose part: Af[:,t] = A[:,t] + A[t,:] (disjoint nonzeros -> OR)
  plo |= spread32((uint32_t)rb0)        | (spread32((uint32_t)rb1)        << 1);
  phi |= spread32((uint32_t)(rb0>>32))  | (spread32((uint32_t)(rb1>>32))  << 1);

  // nonzero-neighbor bitmask for 1-3 connectivity
  uint64_t nzq_lo = (plo | (plo >> 1)) & 0x5555555555555555ull;
  uint64_t nzq_hi = (phi | (phi >> 1)) & 0x5555555555555555ull;
  const uint32_t mk_lo = compress_even(nzq_lo);
  const uint32_t mk_hi = compress_even(nzq_hi);

  // --- Main pairwise loop: all-register + tiny LDS lookups ---
  float ei = 0.f;
  const int aromsel = aromt << 2;
  uint64_t p = plo;
  #pragma unroll
  for (int i = 0; i < 64; ++i){
    if (i == 32) p = phi;
    int af = (int)((uint32_t)p & 3u);
    p >>= 2;
    int arom_i = (int)((aromBits >> i) & 1ull);          // uniform (scalar)
    float bw = bw2[af + (arom_i ? aromsel : 0)];
    uint32_t milo = (uint32_t)__builtin_amdgcn_readlane((int)mk_lo, i);
    uint32_t mihi = (uint32_t)__builtin_amdgcn_readlane((int)mk_hi, i);
    int one3 = (((milo & mk_lo) | (mihi & mk_hi)) != 0u);
    float w = bw + (one3 ? alpha4 : 0.f);
    int ro = __builtin_amdgcn_readlane(tabrow, i);       // type_i * 39 (uniform)
    ei = fmaf(w, tab[ro + ty], ei);
  }

  // --- Analytic charge solve: two wave reductions ---
  float esv = ei * sinv;
  float sv  = sinv;
  #pragma unroll
  for (int off = 32; off; off >>= 1){
    esv += __shfl_xor(esv, off);
    sv  += __shfl_xor(sv,  off);
  }
  const float lam = (Q[m] + esv) / sv;
  out[m*NA + lane] = sinv * (lam - ei);
}

extern "C" void kernel_launch(void* const* d_in, const int* in_sizes, int n_in,
                              void* d_out, int out_size, void* d_ws, size_t ws_size,
                              hipStream_t stream)
{
  const int*   atoms = (const int*)  d_in[0];
  const float* A     = (const float*)d_in[1];
  const float* Q     = (const float*)d_in[2];
  const float* e     = (const float*)d_in[3];
  const float* s     = (const float*)d_in[4];
  const float* alpha = (const float*)d_in[5];
  const float* beta  = (const float*)d_in[6];
  float* out = (float*)d_out;

  const int B = in_sizes[2];                 // Q has one entry per molecule
  const int grid = (B + WPB - 1) / WPB;      // one wave per molecule
  hipLaunchKernelGGL(vcharge_kernel, dim3(grid), dim3(WPB*64), 0, stream,
                     atoms, A, Q, e, s, alpha, beta, out, B);
}